// Round 3
// baseline (262.627 us; speedup 1.0000x reference)
//
#include <hip/hip_runtime.h>

// DNNF fused pipeline for MI355X (gfx950). R8 = 8-phase counted-vmcnt GEMM
// (m201/HK-style port). R6/R7 lesson: the 2-barrier-per-K-step structure is
// the ceiling (~900 TF), not traffic (R6) nor occupancy (R7). New schedule:
// 256x192 tile, BK=64, 8 waves (2m x 4n, per-wave 128x48), 2x56KB LDS dbuf,
// per K-tile 4 phases {ds_read quadrant | stage 64-row units | barrier |
// MFMA (setprio) | lgkmcnt(0)+barrier}, vmcnt(7) only at phases 4/8 so 7
// staged units stay in flight across barriers. R5's zero-conflict 128B-row
// XOR swizzle (pre-swizzled global source, linear LDS dest).

#define BATCH 8192
#define IDIM 512
#define NFORM 256
#define NLIT 10752
#define WT_ROWS 11136  // NLIT + 256 mu + 128 zero pad; /192 = 58 tiles

#define BM 256
#define BN 192
#define BK 64
#define TBUF 57344   // one buffer: A 32768 (256x128B) + B 24576 (192x128B)
#define SLITP 196    // slit row stride (floats)

typedef __bf16 bf16x8 __attribute__((ext_vector_type(8)));
typedef float f32x4 __attribute__((ext_vector_type(4)));
typedef unsigned short u16;
typedef unsigned int u32;

__device__ __forceinline__ u16 f2bf(float f) {
  u32 u = __float_as_uint(f);
  u = (u + 0x7fffu + ((u >> 16) & 1u)) >> 16;  // RNE
  return (u16)u;
}

__device__ __forceinline__ float fast_tanh(float x) {
  float e = __expf(2.0f * x);
  return 1.0f - 2.0f * __builtin_amdgcn_rcpf(e + 1.0f);
}

__device__ __forceinline__ void async_cp16(const void* g, void* l) {
  __builtin_amdgcn_global_load_lds(
      (const u32 __attribute__((address_space(1)))*)g,
      (u32 __attribute__((address_space(3)))*)l, 16, 0, 0);
}

// ---------------- fused prep (one dispatch) ----------------

#define PREPX_BLKS 2048
#define PREPW_BLKS 1344  // 168 l-tiles x 8 k-tiles

__global__ __launch_bounds__(256) void prep_all(
    const float* __restrict__ x, const float* __restrict__ W,
    const float* __restrict__ M, const float* __restrict__ mu,
    u16* __restrict__ xb, u16* __restrict__ wt, float* __restrict__ xsq,
    float* __restrict__ musq, float* __restrict__ form_sum) {
  __shared__ float lds[64 * 65];  // 16.6 KB; also reused as red[256]
  const int blk = blockIdx.x, tid = threadIdx.x;

  if (blk < PREPX_BLKS) {
    ((uint4*)form_sum)[blk * 256 + tid] = make_uint4(0, 0, 0, 0);
    int wave = tid >> 6, lane = tid & 63;
    int row = blk * 4 + wave;
    const float4* px = (const float4*)(x + (size_t)row * IDIM);
    float4 a = px[lane * 2], b = px[lane * 2 + 1];
    uint4 pk;
    pk.x = (u32)f2bf(a.x) | ((u32)f2bf(a.y) << 16);
    pk.y = (u32)f2bf(a.z) | ((u32)f2bf(a.w) << 16);
    pk.z = (u32)f2bf(b.x) | ((u32)f2bf(b.y) << 16);
    pk.w = (u32)f2bf(b.z) | ((u32)f2bf(b.w) << 16);
    ((uint4*)(xb + (size_t)row * IDIM))[lane] = pk;
    float s = a.x * a.x + a.y * a.y + a.z * a.z + a.w * a.w +
              b.x * b.x + b.y * b.y + b.z * b.z + b.w * b.w;
#pragma unroll
    for (int o = 32; o > 0; o >>= 1) s += __shfl_down(s, o);
    if (lane == 0) xsq[row] = s;
  } else if (blk < PREPX_BLKS + PREPW_BLKS) {
    int b = blk - PREPX_BLKS;
    int l0 = (b % 168) * 64, k0 = (b / 168) * 64;
#pragma unroll
    for (int j = 0; j < 4; ++j) {
      int idx = tid + j * 256;
      int kk = idx >> 4, l4 = idx & 15;
      size_t g = (size_t)(k0 + kk) * NLIT + l0 + l4 * 4;
      float4 w4 = *(const float4*)(W + g);
      float4 m4 = *(const float4*)(M + g);
      lds[kk * 65 + l4 * 4 + 0] = w4.x * m4.x;
      lds[kk * 65 + l4 * 4 + 1] = w4.y * m4.y;
      lds[kk * 65 + l4 * 4 + 2] = w4.z * m4.z;
      lds[kk * 65 + l4 * 4 + 3] = w4.w * m4.w;
    }
    __syncthreads();
    int l = tid >> 2, kq = tid & 3;
    u32 pk[8];
#pragma unroll
    for (int t = 0; t < 8; ++t) {
      u16 lo = f2bf(lds[(kq * 16 + 2 * t) * 65 + l]);
      u16 hi = f2bf(lds[(kq * 16 + 2 * t + 1) * 65 + l]);
      pk[t] = (u32)lo | ((u32)hi << 16);
    }
    u32* dst = (u32*)(wt + (size_t)(l0 + l) * IDIM + k0 + kq * 16);
    ((uint4*)dst)[0] = make_uint4(pk[0], pk[1], pk[2], pk[3]);
    ((uint4*)dst)[1] = make_uint4(pk[4], pk[5], pk[6], pk[7]);
  } else {
    int b = blk - PREPX_BLKS - PREPW_BLKS;
    if (b < 256) {
      float s = 0.f;
#pragma unroll
      for (int j = tid; j < IDIM; j += 256) {
        float v = mu[(size_t)b * IDIM + j];
        wt[(size_t)(NLIT + b) * IDIM + j] = f2bf(v);
        s += v * v;
      }
      float* red = lds;
      red[tid] = s;
      __syncthreads();
      for (int sh = 128; sh > 0; sh >>= 1) {
        if (tid < sh) red[tid] += red[tid + sh];
        __syncthreads();
      }
      if (tid == 0) musq[b] = red[0];
    } else {
      int row = NLIT + 256 + (b - 256);  // 11008..11135
      for (int j = tid; j < IDIM; j += 256) wt[(size_t)row * IDIM + j] = 0;
    }
  }
}

// ---------------- main fused GEMM (8-phase, counted vmcnt) ----------------
// Units: A0..A3 = 64-row slabs of the 256-row A tile; B0..B2 of the 192-row
// B tile. Per iteration (2 K-tiles, 8 phases): reads p1:{A-msh0,B-nf01}
// p2:{B-nf2} p3:{A-msh1} p4:{}; stages p2:{cA0,cA2} p3:{cB0..2} p4:{cA1,cA3}
// p6/p7/p8 mirror into buf1. vmcnt(7) at p4/p8 = exactly the 7 loads of the
// current tile's stages stay in flight; everything older has landed.

__global__ __launch_bounds__(512, 2) void dnnf_gemm(
    const u16* __restrict__ xb, const u16* __restrict__ wt,
    const float* __restrict__ bias, float* __restrict__ form_sum,
    float* __restrict__ dotbuf) {
  __shared__ __align__(16) char smraw[2 * TBUF];  // 114688 B
  float* slit = (float*)smraw;                    // epilogue view 128 x SLITP

  const int tid = threadIdx.x;
  const int wave = tid >> 6, lane = tid & 63;
  const int wm = wave >> 2, wn = wave & 3;  // wave tile: 128 rows x 48 cols
  const int m0 = blockIdx.x * BM, n0 = blockIdx.y * BN;
  const int q = lane >> 4, cn = lane & 15;

  // staging: chunk c = tid within a 64-row unit; r = c>>3, kg = (c&7)^(r&7)
  const int sr = tid >> 3;
  const int kgs = ((tid & 7) ^ (sr & 7)) * 8;
  const u16* pa = xb + (size_t)(m0 + sr) * IDIM + kgs;
  const u16* pb = wt + (size_t)(n0 + sr) * IDIM + kgs;
  const int ldsd = tid * 16;

  // fragment read offsets: row*128 + ((q ^ (row&7))<<4), ks toggles ^64
  const int swz = (q ^ (cn & 7)) << 4;
  int offA[8], offB[3];
#pragma unroll
  for (int mf = 0; mf < 8; ++mf)
    offA[mf] = (wm * 128 + mf * 16 + cn) * 128 + swz;
#pragma unroll
  for (int nf = 0; nf < 3; ++nf)
    offB[nf] = 32768 + (wn * 48 + nf * 16 + cn) * 128 + swz;

  f32x4 acc[8][3];
#pragma unroll
  for (int a = 0; a < 8; ++a)
#pragma unroll
    for (int b = 0; b < 3; ++b) acc[a][b] = (f32x4){0.f, 0.f, 0.f, 0.f};

  bf16x8 af[4][2], bfr[3][2];

#define STG_A(bi, u, t)                                  \
  async_cp16(pa + (size_t)(u) * 64 * IDIM + (t) * BK,    \
             smraw + (bi) * TBUF + (u) * 8192 + ldsd)
#define STG_B(bi, u, t)                                  \
  async_cp16(pb + (size_t)(u) * 64 * IDIM + (t) * BK,    \
             smraw + (bi) * TBUF + 32768 + (u) * 8192 + ldsd)
#define RD_A(bi, msh)                                               \
  do {                                                              \
    const char* bp_ = smraw + (bi) * TBUF;                          \
    _Pragma("unroll") for (int i_ = 0; i_ < 4; ++i_) {              \
      af[i_][0] = *(const bf16x8*)(bp_ + offA[(msh) * 4 + i_]);     \
      af[i_][1] = *(const bf16x8*)(bp_ + (offA[(msh) * 4 + i_] ^ 64)); \
    }                                                               \
  } while (0)
#define RD_B01(bi)                                                  \
  do {                                                              \
    const char* bp_ = smraw + (bi) * TBUF;                          \
    _Pragma("unroll") for (int j_ = 0; j_ < 2; ++j_) {              \
      bfr[j_][0] = *(const bf16x8*)(bp_ + offB[j_]);                \
      bfr[j_][1] = *(const bf16x8*)(bp_ + (offB[j_] ^ 64));         \
    }                                                               \
  } while (0)
#define RD_B2(bi)                                                   \
  do {                                                              \
    const char* bp_ = smraw + (bi) * TBUF;                          \
    bfr[2][0] = *(const bf16x8*)(bp_ + offB[2]);                    \
    bfr[2][1] = *(const bf16x8*)(bp_ + (offB[2] ^ 64));             \
  } while (0)
#define MM(msh, nflo, nfhi)                                         \
  do {                                                              \
    __builtin_amdgcn_s_setprio(1);                                  \
    _Pragma("unroll") for (int i_ = 0; i_ < 4; ++i_)                \
    _Pragma("unroll") for (int n_ = (nflo); n_ <= (nfhi); ++n_)     \
    _Pragma("unroll") for (int k_ = 0; k_ < 2; ++k_)                \
      acc[(msh) * 4 + i_][n_] = __builtin_amdgcn_mfma_f32_16x16x32_bf16( \
          af[i_][k_], bfr[n_][k_], acc[(msh) * 4 + i_][n_], 0, 0, 0);    \
    __builtin_amdgcn_s_setprio(0);                                  \
  } while (0)
#define BAR asm volatile("s_barrier" ::: "memory")
#define BARV asm volatile("s_waitcnt vmcnt(7)\n\ts_barrier" ::: "memory")
#define BARL asm volatile("s_waitcnt lgkmcnt(0)\n\ts_barrier" ::: "memory")

  // prologue: T0 -> buf0 (7 units), T1 -> buf1 (7 units); wait T0
#pragma unroll
  for (int u = 0; u < 4; ++u) STG_A(0, u, 0);
#pragma unroll
  for (int u = 0; u < 3; ++u) STG_B(0, u, 0);
#pragma unroll
  for (int u = 0; u < 4; ++u) STG_A(1, u, 1);
#pragma unroll
  for (int u = 0; u < 3; ++u) STG_B(1, u, 1);
  BARV;

#pragma unroll
  for (int it = 0; it < 4; ++it) {
    const int s0 = 2 * it + 2, s1 = 2 * it + 3;  // stage tiles (guard it<3)
    // ---- K-tile 2it (buf0) ----
    // p1
    RD_A(0, 0);
    RD_B01(0);
    BAR;
    MM(0, 0, 1);
    BARL;
    // p2
    RD_B2(0);
    if (it < 3) { STG_A(0, 0, s0); STG_A(0, 2, s0); }
    BAR;
    MM(0, 2, 2);
    BARL;
    // p3
    RD_A(0, 1);
    if (it < 3) { STG_B(0, 0, s0); STG_B(0, 1, s0); STG_B(0, 2, s0); }
    BAR;
    MM(1, 0, 1);
    BARL;
    // p4
    if (it < 3) { STG_A(0, 1, s0); STG_A(0, 3, s0); }
    BARV;
    MM(1, 2, 2);
    BAR;
    // ---- K-tile 2it+1 (buf1) ----
    // p5
    RD_A(1, 0);
    RD_B01(1);
    BAR;
    MM(0, 0, 1);
    BARL;
    // p6
    RD_B2(1);
    if (it < 3) { STG_A(1, 0, s1); STG_A(1, 2, s1); }
    BAR;
    MM(0, 2, 2);
    BARL;
    // p7
    RD_A(1, 1);
    if (it < 3) { STG_B(1, 0, s1); STG_B(1, 1, s1); STG_B(1, 2, s1); }
    BAR;
    MM(1, 0, 1);
    BARL;
    // p8
    if (it < 3) { STG_A(1, 1, s1); STG_A(1, 3, s1); }
    BARV;
    MM(1, 2, 2);
    BAR;
  }
  __syncthreads();  // full drain before LDS reuse as slit

  if (n0 < NLIT) {
    float bv[3];
#pragma unroll
    for (int nf = 0; nf < 3; ++nf) bv[nf] = bias[n0 + wn * 48 + nf * 16 + cn];

    // two phases of 128 rows; slit tile 128 x SLITP (100 KB <= 112 KB)
#pragma unroll
    for (int ph = 0; ph < 2; ++ph) {
      if (ph) __syncthreads();  // prev-phase reads done before overwrite
      if (wm == ph) {
#pragma unroll
        for (int nf = 0; nf < 3; ++nf) {
          int col = wn * 48 + nf * 16 + cn;
#pragma unroll
          for (int mf = 0; mf < 8; ++mf)
#pragma unroll
            for (int reg = 0; reg < 4; ++reg) {
              int lr = mf * 16 + q * 4 + reg;
              slit[lr * SLITP + col] = fast_tanh(acc[mf][nf][reg] + bv[nf]);
            }
        }
      }
      __syncthreads();

      int rr = tid >> 2, sub = tid & 3;  // 128 rows x 4 threads (48 lits)
      const float* lrow = slit + rr * SLITP + sub * 48;
      int c0 = ((n0 + sub * 48) / 12) * 3;
      size_t grow = (size_t)(m0 + ph * 128 + rr) * NFORM;
      float run = 0.f;
      int fprev = -1;
#pragma unroll
      for (int tr = 0; tr < 4; ++tr) {
        const float4 a0 = *(const float4*)(lrow + tr * 12);
        const float4 a1 = *(const float4*)(lrow + tr * 12 + 4);
        const float4 a2 = *(const float4*)(lrow + tr * 12 + 8);
        float s2 = a0.x + a0.y;
        float s4 = a0.z + a0.w + a1.x + a1.y;
        float s6 = a1.z + a1.w + a2.x + a2.y + a2.z + a2.w;
        float v = fast_tanh(s2 - 0.5f) + fast_tanh(s4 - 2.5f) +
                  fast_tanh(s6 - 4.5f);
        int c = c0 + tr * 3;
        int f = (c < 384)    ? (c / 6)
                : (c < 960)  ? 64 + (c - 384) / 9
                : (c < 1728) ? 128 + (c - 960) / 12
                             : 192 + (c - 1728) / 15;
        if (f != fprev) {
          if (fprev >= 0) atomicAdd(form_sum + grow + fprev, run);
          fprev = f;
          run = 0.f;
        }
        run += v;
      }
      atomicAdd(form_sum + grow + fprev, run);
    }
  } else {
    // mu tiles: store raw x.mu dots
#pragma unroll
    for (int nf = 0; nf < 3; ++nf) {
      int col = n0 - NLIT + wn * 48 + nf * 16 + cn;
      if (col < NFORM) {
#pragma unroll
        for (int mf = 0; mf < 8; ++mf)
#pragma unroll
          for (int reg = 0; reg < 4; ++reg) {
            int row = wm * 128 + mf * 16 + q * 4 + reg;
            dotbuf[(size_t)(m0 + row) * NFORM + col] = acc[mf][nf][reg];
          }
      }
    }
  }
}

// ---------------- finale: RBF softmax * dnnf (wave-per-row) ----------------

__global__ __launch_bounds__(256) void finale(
    const float* __restrict__ form_sum, const float* __restrict__ dotbuf,
    const float* __restrict__ xsq, const float* __restrict__ musq,
    const float* __restrict__ sigma, float* __restrict__ out) {
  int wave = threadIdx.x >> 6, lane = threadIdx.x & 63;
  int r = blockIdx.x * 4 + wave;
  size_t base = (size_t)r * NFORM;
  float xs = xsq[r];
  float e[4], s = 0.f;
#pragma unroll
  for (int j = 0; j < 4; ++j) {
    int f = j * 64 + lane;
    float sq = xs - 2.0f * dotbuf[base + f] + musq[f];
    float sg = sigma[f];
    float p = __expf(-0.5f * sq / (sg * sg));
    e[j] = __expf(2.0f * p);  // TEMPERATURE=2; values in [1, e^2]
    s += e[j];
  }
#pragma unroll
  for (int o = 32; o > 0; o >>= 1) s += __shfl_xor(s, o);
  float inv = __builtin_amdgcn_rcpf(s);
#pragma unroll
  for (int j = 0; j < 4; ++j) {
    int f = j * 64 + lane;
    float dn = fast_tanh(form_sum[base + f] + (float)(6 + 3 * j) - 1.5f);
    out[base + f] = dn * e[j] * inv;
  }
}

// ---------------- launch ----------------

extern "C" void kernel_launch(void* const* d_in, const int* in_sizes, int n_in,
                              void* d_out, int out_size, void* d_ws,
                              size_t ws_size, hipStream_t stream) {
  const float* x = (const float*)d_in[0];
  const float* W = (const float*)d_in[1];
  const float* M = (const float*)d_in[2];
  const float* bias = (const float*)d_in[3];
  const float* mu = (const float*)d_in[4];
  const float* sigma = (const float*)d_in[5];
  float* out = (float*)d_out;

  float* form_sum = (float*)d_ws;                       // 8 MB
  float* dotbuf = form_sum + (size_t)BATCH * NFORM;     // 8 MB
  u16* xb = (u16*)(dotbuf + (size_t)BATCH * NFORM);     // 8 MB
  u16* wt = xb + (size_t)BATCH * IDIM;                  // 11.4 MB
  float* xsq = (float*)(wt + (size_t)WT_ROWS * IDIM);   // 32 KB
  float* musq = xsq + BATCH;                            // 1 KB

  prep_all<<<PREPX_BLKS + PREPW_BLKS + 384, 256, 0, stream>>>(
      x, W, M, mu, xb, wt, xsq, musq, form_sum);
  // grid: x = m (32, multiple of 8 -> XCD-pinned m-tiles), y = n (58)
  dnnf_gemm<<<dim3(BATCH / BM, WT_ROWS / BN), 512, 0, stream>>>(xb, wt, bias,
                                                                form_sum, dotbuf);
  finale<<<BATCH / 4, 256, 0, stream>>>(form_sum, dotbuf, xsq, musq, sigma, out);
}